// Round 9
// baseline (103.718 us; speedup 1.0000x reference)
//
#include <hip/hip_runtime.h>
#include <hip/hip_bf16.h>
#include <stdint.h>

#define HSZ 2048
#define PRIME 500009u
#define CHUNK 64   // K-floats staged per iteration (256 B/row)
#define NCH 32     // 2048 / 64

typedef __attribute__((ext_vector_type(8))) short short8;
typedef __attribute__((ext_vector_type(4))) float f32x4;
typedef __attribute__((ext_vector_type(4))) unsigned uint4v;
typedef __attribute__((ext_vector_type(2))) unsigned uint2v;

#define MEMFENCE asm volatile("" ::: "memory")
#define BARRIER() do { MEMFENCE; __builtin_amdgcn_s_barrier(); MEMFENCE; } while (0)
#define WAIT_LGKM0 asm volatile("s_waitcnt lgkmcnt(0)" ::: "memory")
#define WAIT_VM(n) asm volatile("s_waitcnt vmcnt(" #n ")" ::: "memory")

__device__ __forceinline__ unsigned pk2(float x, float y) {
  __hip_bfloat162 h = __float22bfloat162_rn(make_float2(x, y));
  return *reinterpret_cast<unsigned*>(&h);
}
__device__ __forceinline__ short f2bf(float f) {
  __hip_bfloat16 h = __float2bfloat16(f);
  return *reinterpret_cast<short*>(&h);
}
__device__ __forceinline__ short8 pack8(float4 a, float4 b) {
  uint4v u = {pk2(a.x, a.y), pk2(a.z, a.w), pk2(b.x, b.y), pk2(b.z, b.w)};
  return __builtin_bit_cast(short8, u);
}
__device__ __forceinline__ short8 load8_bf(const float* __restrict__ p) {
  float4 a = *reinterpret_cast<const float4*>(p);
  float4 b = *reinterpret_cast<const float4*>(p + 4);
  return pack8(a, b);
}
__device__ __forceinline__ void gload_lds16(const float* g, void* l) {
  __builtin_amdgcn_global_load_lds(
      (const __attribute__((address_space(1))) void*)g,
      (__attribute__((address_space(3))) void*)l, 16, 0, 0);
}

// ============ fused kernel: 512 blocks x 256 threads, 32 tokens/block ============
// R8 base + token-split back half: MLP(rows 0-15) -> [MLP(rows 16-31) zipped with
// out(rows 0-15)] -> out(rows 16-31). The zipped middle overlaps the HBM read
// stream with the write stream to fill per-phase bubbles.
__global__ __launch_bounds__(256, 2) void engram_fused(
    const int* __restrict__ ids, const int* __restrict__ mapping,
    const unsigned* __restrict__ mult, const float* __restrict__ table,
    const float* __restrict__ Wh, const float* __restrict__ hidden,
    const float* __restrict__ cw, const float* __restrict__ cb,
    const float* __restrict__ Wg, const float* __restrict__ Wo,
    float* __restrict__ out) {
  __shared__ __align__(16) float hbuf[2][16][CHUNK];   // 8 KB hidden dbuf (16 rows)
  __shared__ __align__(16) float wgbuf[2][32][CHUNK];  // 16 KB Wg dbuf
  __shared__ __align__(16) short A_lds[48][264];       // gathered table rows, bf16
  __shared__ __align__(16) float emb48[48][36];        // emb0 for 48 slots
  __shared__ float emb_c[32][33];                      // conv output
  __shared__ __align__(16) short ge_lds[32][40];       // gate*emb bf16
  __shared__ float accred[2][4][64];                   // K-half reduce
  __shared__ int idx_lds[384];                         // 48 slots x 8 heads

  const int tid = threadIdx.x;
  const int wid = tid >> 6, lane = tid & 63;
  const int l16 = lane & 15, q = lane >> 4;
  const int t0 = blockIdx.x * 32;

  // stage one K-chunk: hidden rows [t0+ro, +16) (4 instrs, 1/wave) and Wg rows 0..31
  // (8 instrs, 2/wave) -> 3 vmem instrs per wave. LDS dest linear; global source
  // col byte-XOR-swizzled by ((row&7)<<4); read side applies the same XOR.
  auto STAGE = [&](int buf, int kc, int ro) {
    {
      int r0 = wid * 4;
      int r = r0 + (lane >> 4);
      unsigned c4 = (((unsigned)l16 * 16u) ^ (((unsigned)r & 7u) << 4)) >> 2;
      gload_lds16(hidden + (size_t)(t0 + ro + r) * HSZ + kc * CHUNK + c4,
                  &hbuf[buf][r0][0]);
    }
#pragma unroll
    for (int j = 0; j < 2; ++j) {
      int r0 = wid * 8 + j * 4;
      int r = r0 + (lane >> 4);
      unsigned c4 = (((unsigned)l16 * 16u) ^ (((unsigned)r & 7u) << 4)) >> 2;
      gload_lds16(Wg + (size_t)r * HSZ + kc * CHUNK + c4, &wgbuf[buf][r0][0]);
    }
  };

  STAGE(0, 0, 0);
  STAGE(1, 1, 0);  // chunks 0,1 (rows 0-15) fly under the whole front-end

  // ---- 1) hash: 48 slots x 8 heads; slot i = token t0-16+i (clamped) ----
#pragma unroll
  for (int p = 0; p < 2; ++p) {
    int hh = p * 256 + tid;
    if (hh < 384) {
      int slot = hh >> 3, head = hh & 7;
      int tg = t0 - 16 + slot;
      if (tg < 0) tg = 0;
      int b = tg >> 12, s = tg & 4095;
      const int* idb = ids + (b << 12);
      int s1 = s + 1 > 4095 ? 4095 : s + 1;
      int s2 = s + 2 > 4095 ? 4095 : s + 2;
      uint64_t c0 = (unsigned)mapping[idb[s]];
      uint64_t c1 = (unsigned)mapping[idb[s1]];
      uint64_t c2 = (unsigned)mapping[idb[s2]];
      int mb = head * 3;  // multipliers row-major [2][4][3]
      uint64_t h = (c0 * (uint64_t)mult[mb]) ^ (c1 * (uint64_t)mult[mb + 1]);
      if (head >= 4) h ^= c2 * (uint64_t)mult[mb + 2];
      idx_lds[hh] = (int)((unsigned)(h % PRIME) + (unsigned)head * PRIME);
    }
  }
  WAIT_LGKM0; BARRIER();

  // ---- 2) gather 384 table rows (128 B each, 8 lanes/row) -> A_lds bf16 ----
#pragma unroll
  for (int p = 0; p < 12; ++p) {
    int r = p * 32 + (tid >> 3);
    int c4 = (tid & 7) * 4;
    int row = idx_lds[r];
    float4 v = *reinterpret_cast<const float4*>(table + (size_t)row * 32 + c4);
    uint2v pk = {pk2(v.x, v.y), pk2(v.z, v.w)};
    *reinterpret_cast<uint2v*>(&A_lds[r >> 3][(r & 7) * 32 + c4]) = pk;
  }
  WAIT_LGKM0; BARRIER();

  // ---- 3) emb0 MFMA: 6 jobs (3 slot-tiles x 2 e-tiles), swapped operands ----
  for (int job = wid; job < 6; job += 4) {
    int jt = job >> 1, e0 = (job & 1) * 16;
    f32x4 acc = {0.f, 0.f, 0.f, 0.f};
#pragma unroll
    for (int ks = 0; ks < 8; ++ks) {
      short8 wf = load8_bf(Wh + (size_t)(e0 + l16) * 256 + ks * 32 + q * 8);
      short8 a = *reinterpret_cast<const short8*>(&A_lds[jt * 16 + l16][ks * 32 + q * 8]);
      acc = __builtin_amdgcn_mfma_f32_16x16x32_bf16(wf, a, acc, 0, 0, 0);
    }
    *reinterpret_cast<f32x4*>(&emb48[jt * 16 + l16][e0 + q * 4]) = acc;
  }
  WAIT_LGKM0; BARRIER();

  // ---- 4) conv: emb_c[tl][e] = cb + sum_j cw[e,j]*emb48[13+tl+j][e] ----
#pragma unroll
  for (int it = 0; it < 4; ++it) {
    int ii = it * 256 + tid;
    int tl = ii >> 5, e = ii & 31;
    int s = (t0 & 4095) + tl;
    float a = cb[e];
#pragma unroll
    for (int j = 0; j < 4; ++j)
      if (s - 3 + j >= 0) a += cw[e * 4 + j] * emb48[13 + tl + j][e];
    emb_c[tl][e] = a;
  }
  WAIT_LGKM0; BARRIER();

  // ---- wave roles for the back half: (ee = e-tile, kh = K-half of each chunk) ----
  const int ee = wid & 1, kh = wid >> 1;
  const unsigned swA = ((unsigned)l16 & 7u) << 4;
  const int Rb = ee * 16 + l16;
  const unsigned swB = ((unsigned)Rb & 7u) << 4;
  const unsigned x0 = (unsigned)(kh * 128 + q * 32);
  const char* hA0 = (const char*)&hbuf[0][l16][0];
  const char* hA1 = (const char*)&hbuf[1][l16][0];
  const char* wB0 = (const char*)&wgbuf[0][Rb][0];
  const char* wB1 = (const char*)&wgbuf[1][Rb][0];
  f32x4 z = {0.f, 0.f, 0.f, 0.f};

  // ---- 5) loop 1: MLP rows 0-15, 1 MFMA/iter/wave; counted vmcnt(3) ----
  f32x4 accA = {0.f, 0.f, 0.f, 0.f};
  for (int kc = 0; kc < 31; ++kc) {
    WAIT_VM(3);   // stage(kc) landed; stage(kc+1)'s 3 instrs may fly
    BARRIER();
    const char* hb = (kc & 1) ? hA1 : hA0;
    const char* wb = (kc & 1) ? wB1 : wB0;
    float4 a0 = *reinterpret_cast<const float4*>(hb + (x0 ^ swA));
    float4 a1 = *reinterpret_cast<const float4*>(hb + ((x0 + 16) ^ swA));
    float4 b0 = *reinterpret_cast<const float4*>(wb + (x0 ^ swB));
    float4 b1 = *reinterpret_cast<const float4*>(wb + ((x0 + 16) ^ swB));
    short8 A = pack8(a0, a1), B = pack8(b0, b1);
    WAIT_LGKM0; BARRIER();
    if (kc < 30) STAGE(kc & 1, kc + 2, 0);
    accA = __builtin_amdgcn_mfma_f32_16x16x32_bf16(A, B, accA, 0, 0, 0);
  }
  {  // kc = 31 (odd -> buf1), full drain
    WAIT_VM(0); BARRIER();
    float4 a0 = *reinterpret_cast<const float4*>(hA1 + (x0 ^ swA));
    float4 a1 = *reinterpret_cast<const float4*>(hA1 + ((x0 + 16) ^ swA));
    float4 b0 = *reinterpret_cast<const float4*>(wB1 + (x0 ^ swB));
    float4 b1 = *reinterpret_cast<const float4*>(wB1 + ((x0 + 16) ^ swB));
    accA = __builtin_amdgcn_mfma_f32_16x16x32_bf16(pack8(a0, a1), pack8(b0, b1), accA, 0, 0, 0);
  }

  // ---- reduce A + sigmoid*emb -> ge rows 0-15; prologue for loop 2 flies under ----
  if (kh == 1) {
#pragma unroll
    for (int j = 0; j < 4; ++j) accred[ee][j][lane] = accA[j];
  }
  WAIT_LGKM0; BARRIER();  // all loop-1 LDS reads complete -> safe to restage buffers
  short8 wo_cur = load8_bf(Wo + (size_t)(wid * 512 + l16) * 32 + q * 8);  // Wo(ht=0)
  STAGE(0, 0, 16);
  STAGE(1, 1, 16);        // rows 16-31, chunks 0,1 fly under the reduce/sigmoid
  if (kh == 0) {
#pragma unroll
    for (int j = 0; j < 4; ++j) {
      float s = accA[j] + accred[ee][j][lane];
      int r = q * 4 + j, c = ee * 16 + l16;
      float g = 1.f / (1.f + __expf(-s));
      ge_lds[r][c] = f2bf(g * emb_c[r][c]);
    }
  }
  WAIT_LGKM0; BARRIER();
  short8 AfA = *reinterpret_cast<const short8*>(&ge_lds[l16][q * 8]);
  float* orowA = out + (size_t)(t0 + l16) * HSZ;

  // ---- 6) loop 2: MLP rows 16-31 zipped with out rows 0-15 (1 ht/iter/wave) ----
  f32x4 accB = {0.f, 0.f, 0.f, 0.f};
  {  // kc = 0 peel: queue = [Wo0:2][sB0:3][sB1:3] -> allow 3 (sB1)
    WAIT_VM(3); BARRIER();
    float4 a0 = *reinterpret_cast<const float4*>(hA0 + (x0 ^ swA));
    float4 a1 = *reinterpret_cast<const float4*>(hA0 + ((x0 + 16) ^ swA));
    float4 b0 = *reinterpret_cast<const float4*>(wB0 + (x0 ^ swB));
    float4 b1 = *reinterpret_cast<const float4*>(wB0 + ((x0 + 16) ^ swB));
    short8 A = pack8(a0, a1), B = pack8(b0, b1);
    WAIT_LGKM0; BARRIER();
    f32x4 o = __builtin_amdgcn_mfma_f32_16x16x32_bf16(wo_cur, AfA, z, 0, 0, 0);
    *reinterpret_cast<f32x4*>(orowA + wid * 512 + q * 4) = o;
    wo_cur = load8_bf(Wo + (size_t)(wid * 512 + 16 + l16) * 32 + q * 8);
    STAGE(0, 2, 16);
    accB = __builtin_amdgcn_mfma_f32_16x16x32_bf16(A, B, accB, 0, 0, 0);
  }
  for (int kc = 1; kc <= 30; ++kc) {
    WAIT_VM(6);   // younger-than-stage(kc): store+Wo(2)+stage(kc+1)(3) = 6
    BARRIER();
    const char* hb = (kc & 1) ? hA1 : hA0;
    const char* wb = (kc & 1) ? wB1 : wB0;
    float4 a0 = *reinterpret_cast<const float4*>(hb + (x0 ^ swA));
    float4 a1 = *reinterpret_cast<const float4*>(hb + ((x0 + 16) ^ swA));
    float4 b0 = *reinterpret_cast<const float4*>(wb + (x0 ^ swB));
    float4 b1 = *reinterpret_cast<const float4*>(wb + ((x0 + 16) ^ swB));
    short8 A = pack8(a0, a1), B = pack8(b0, b1);
    WAIT_LGKM0; BARRIER();
    f32x4 o = __builtin_amdgcn_mfma_f32_16x16x32_bf16(wo_cur, AfA, z, 0, 0, 0);
    *reinterpret_cast<f32x4*>(orowA + wid * 512 + kc * 16 + q * 4) = o;
    wo_cur = load8_bf(Wo + (size_t)(wid * 512 + (kc + 1) * 16 + l16) * 32 + q * 8);
    if (kc < 30) STAGE(kc & 1, kc + 2, 16);
    accB = __builtin_amdgcn_mfma_f32_16x16x32_bf16(A, B, accB, 0, 0, 0);
  }
  {  // kc = 31 peel: younger-than-stage(31) = store(30)+Wo(31)(2) = 3
    WAIT_VM(3); BARRIER();
    float4 a0 = *reinterpret_cast<const float4*>(hA1 + (x0 ^ swA));
    float4 a1 = *reinterpret_cast<const float4*>(hA1 + ((x0 + 16) ^ swA));
    float4 b0 = *reinterpret_cast<const float4*>(wB1 + (x0 ^ swB));
    float4 b1 = *reinterpret_cast<const float4*>(wB1 + ((x0 + 16) ^ swB));
    short8 A = pack8(a0, a1), B = pack8(b0, b1);
    WAIT_LGKM0; BARRIER();
    f32x4 o = __builtin_amdgcn_mfma_f32_16x16x32_bf16(wo_cur, AfA, z, 0, 0, 0);
    *reinterpret_cast<f32x4*>(orowA + wid * 512 + 31 * 16 + q * 4) = o;
    accB = __builtin_amdgcn_mfma_f32_16x16x32_bf16(A, B, accB, 0, 0, 0);
  }

  // ---- reduce B + sigmoid*emb -> ge rows 16-31 ----
  if (kh == 1) {
#pragma unroll
    for (int j = 0; j < 4; ++j) accred[ee][j][lane] = accB[j];
  }
  WAIT_LGKM0; BARRIER();
  if (kh == 0) {
#pragma unroll
    for (int j = 0; j < 4; ++j) {
      float s = accB[j] + accred[ee][j][lane];
      int r = q * 4 + j, c = ee * 16 + l16;
      float g = 1.f / (1.f + __expf(-s));
      ge_lds[16 + r][c] = f2bf(g * emb_c[16 + r][c]);
    }
  }
  WAIT_LGKM0; BARRIER();

  // ---- 7) out tail: rows 16-31, 32 ht/wave ----
  short8 AfB = *reinterpret_cast<const short8*>(&ge_lds[16 + l16][q * 8]);
  float* orowB = out + (size_t)(t0 + 16 + l16) * HSZ;
#pragma unroll 4
  for (int ht = 0; ht < 32; ++ht) {
    int h0 = wid * 512 + ht * 16;
    short8 aw = load8_bf(Wo + (size_t)(h0 + l16) * 32 + q * 8);
    f32x4 o = __builtin_amdgcn_mfma_f32_16x16x32_bf16(aw, AfB, z, 0, 0, 0);
    *reinterpret_cast<f32x4*>(orowB + h0 + q * 4) = o;
  }
}

extern "C" void kernel_launch(void* const* d_in, const int* in_sizes, int n_in,
                              void* d_out, int out_size, void* d_ws, size_t ws_size,
                              hipStream_t stream) {
  const int* ids = (const int*)d_in[0];
  const float* hidden = (const float*)d_in[1];
  const int* mapping = (const int*)d_in[2];
  const unsigned* mult = (const unsigned*)d_in[3];  // delivered as int32; low bits exact
  const float* table = (const float*)d_in[4];
  const float* cw = (const float*)d_in[5];
  const float* cb = (const float*)d_in[6];
  const float* Wh = (const float*)d_in[7];
  const float* Wg = (const float*)d_in[8];
  const float* Wo = (const float*)d_in[9];
  float* out = (float*)d_out;

  engram_fused<<<512, 256, 0, stream>>>(ids, mapping, mult, table, Wh, hidden,
                                        cw, cb, Wg, Wo, out);
}

// Round 10
// 75.388 us; speedup vs baseline: 1.3758x; 1.3758x over previous
//
#include <hip/hip_runtime.h>
#include <hip/hip_bf16.h>
#include <stdint.h>

#define HSZ 2048
#define PRIME 500009u
#define CHUNK 64   // K-floats staged per iteration (256 B/row)
#define NCH 32     // 2048 / 64

typedef __attribute__((ext_vector_type(8))) short short8;
typedef __attribute__((ext_vector_type(4))) float f32x4;
typedef __attribute__((ext_vector_type(4))) unsigned uint4v;
typedef __attribute__((ext_vector_type(2))) unsigned uint2v;

#define MEMFENCE asm volatile("" ::: "memory")
#define BARRIER() do { MEMFENCE; __builtin_amdgcn_s_barrier(); MEMFENCE; } while (0)
#define WAIT_LGKM0 asm volatile("s_waitcnt lgkmcnt(0)" ::: "memory")
#define WAIT_VM(n) asm volatile("s_waitcnt vmcnt(" #n ")" ::: "memory")

__device__ __forceinline__ unsigned pk2(float x, float y) {
  __hip_bfloat162 h = __float22bfloat162_rn(make_float2(x, y));
  return *reinterpret_cast<unsigned*>(&h);
}
__device__ __forceinline__ short f2bf(float f) {
  __hip_bfloat16 h = __float2bfloat16(f);
  return *reinterpret_cast<short*>(&h);
}
__device__ __forceinline__ short8 pack8(float4 a, float4 b) {
  uint4v u = {pk2(a.x, a.y), pk2(a.z, a.w), pk2(b.x, b.y), pk2(b.z, b.w)};
  return __builtin_bit_cast(short8, u);
}
__device__ __forceinline__ short8 load8_bf(const float* __restrict__ p) {
  float4 a = *reinterpret_cast<const float4*>(p);
  float4 b = *reinterpret_cast<const float4*>(p + 4);
  return pack8(a, b);
}
__device__ __forceinline__ void gload_lds16(const float* g, void* l) {
  __builtin_amdgcn_global_load_lds(
      (const __attribute__((address_space(1))) void*)g,
      (__attribute__((address_space(3))) void*)l, 16, 0, 0);
}

// ============ fused kernel: 512 blocks x 256 threads, 32 tokens/block ============
// R8 base + gather-under-MLP: table rows are loaded into VGPRs BEFORE the MLP
// staging chain (in-order vmcnt -> iter-0 wait absorbs the whole gather latency
// once), and the emb0/conv front-end moves AFTER the MLP loop. Lookback trimmed
// to 4 slots (36 slots, 288 rows: -25% gather traffic). MLP wait fixed to vm(3).
__global__ __launch_bounds__(256, 2) void engram_fused(
    const int* __restrict__ ids, const int* __restrict__ mapping,
    const unsigned* __restrict__ mult, const float* __restrict__ table,
    const float* __restrict__ Wh, const float* __restrict__ hidden,
    const float* __restrict__ cw, const float* __restrict__ cb,
    const float* __restrict__ Wg, const float* __restrict__ Wo,
    float* __restrict__ out) {
  __shared__ __align__(16) float hbuf[2][32][CHUNK];   // 16 KB hidden dbuf
  __shared__ __align__(16) float wgbuf[2][32][CHUNK];  // 16 KB Wg dbuf
  __shared__ __align__(16) short A_lds[36][264];       // gathered rows, bf16 (19 KB)
  __shared__ __align__(16) float emb36[36][36];        // emb0 for 36 slots
  __shared__ float emb_c[32][33];                      // conv output
  __shared__ __align__(16) short ge_lds[32][40];       // gate*emb bf16
  __shared__ int idx_lds[288];                         // 36 slots x 8 heads

  const int tid = threadIdx.x;
  const int wid = tid >> 6, lane = tid & 63;
  const int l16 = lane & 15, q = lane >> 4;
  const int t0 = blockIdx.x * 32;

  // stage one K-chunk: hidden rows t0..t0+31 and Wg rows 0..31 (256 B/row).
  // LDS dest linear; global src col byte-XOR-swizzled by ((row&7)<<4).
  auto STAGE = [&](int buf, int kc) {
#pragma unroll
    for (int j = 0; j < 2; ++j) {
      int r0 = wid * 8 + j * 4;
      int r = r0 + (lane >> 4);
      unsigned c4 = (((unsigned)l16 * 16u) ^ (((unsigned)r & 7u) << 4)) >> 2;
      gload_lds16(hidden + (size_t)(t0 + r) * HSZ + kc * CHUNK + c4,
                  &hbuf[buf][r0][0]);
    }
#pragma unroll
    for (int j = 0; j < 2; ++j) {
      int r0 = wid * 8 + j * 4;
      int r = r0 + (lane >> 4);
      unsigned c4 = (((unsigned)l16 * 16u) ^ (((unsigned)r & 7u) << 4)) >> 2;
      gload_lds16(Wg + (size_t)r * HSZ + kc * CHUNK + c4, &wgbuf[buf][r0][0]);
    }
  };

  // ---- 1) hash: 36 slots x 8 heads = 288; slot s = token t0-4+s (clamped) ----
#pragma unroll
  for (int p = 0; p < 2; ++p) {
    int hh = p * 256 + tid;
    if (hh < 288) {
      int slot = hh >> 3, head = hh & 7;
      int tg = t0 - 4 + slot;
      if (tg < 0) tg = 0;
      int b = tg >> 12, s = tg & 4095;
      const int* idb = ids + (b << 12);
      int s1 = s + 1 > 4095 ? 4095 : s + 1;
      int s2 = s + 2 > 4095 ? 4095 : s + 2;
      uint64_t c0 = (unsigned)mapping[idb[s]];
      uint64_t c1 = (unsigned)mapping[idb[s1]];
      uint64_t c2 = (unsigned)mapping[idb[s2]];
      int mb = head * 3;  // multipliers row-major [2][4][3]
      uint64_t h = (c0 * (uint64_t)mult[mb]) ^ (c1 * (uint64_t)mult[mb + 1]);
      if (head >= 4) h ^= c2 * (uint64_t)mult[mb + 2];
      idx_lds[hh] = (int)((unsigned)(h % PRIME) + (unsigned)head * PRIME);
    }
  }
  WAIT_LGKM0; BARRIER();

  // ---- 2) issue gather: 288 rows x 128 B, 9 float4/thread, HELD in VGPRs ----
  float4 g[9];
#pragma unroll
  for (int p = 0; p < 9; ++p) {
    int task = p * 256 + tid;          // 2304 tasks = 288 rows x 8 lane-groups
    int r = task >> 3, c4 = (task & 7) * 4;
    int row = idx_lds[r];
    g[p] = *reinterpret_cast<const float4*>(table + (size_t)row * 32 + c4);
  }

  // ---- 3) stage chunks 0,1 (younger than gathers -> iter-0 wait retires them) ----
  STAGE(0, 0);
  STAGE(1, 1);

  // ---- 4) gate MLP: wave (tt,ee) owns 16x16 tile, full K; vmem-clean loop ----
  const int tt = wid >> 1, ee = wid & 1;
  const int R = tt * 16 + l16;
  const unsigned sw = ((unsigned)R & 7u) << 4;
  const char* hb0 = (const char*)&hbuf[0][R][0];
  const char* hb1 = (const char*)&hbuf[1][R][0];
  const int Rb = ee * 16 + l16;
  const unsigned swb = ((unsigned)Rb & 7u) << 4;
  const char* wb0 = (const char*)&wgbuf[0][Rb][0];
  const char* wb1 = (const char*)&wgbuf[1][Rb][0];
  f32x4 acc = {0.f, 0.f, 0.f, 0.f};

  for (int kc = 0; kc < NCH - 1; ++kc) {
    WAIT_VM(3);   // stage(kc) landed; exactly stage(kc+1)'s 3 instrs may fly
    BARRIER();
    const char* hb = (kc & 1) ? hb1 : hb0;
    const char* wb = (kc & 1) ? wb1 : wb0;
    unsigned x0 = q * 32u;
    float4 a0 = *reinterpret_cast<const float4*>(hb + (x0 ^ sw));
    float4 a1 = *reinterpret_cast<const float4*>(hb + ((x0 + 16) ^ sw));
    float4 a2 = *reinterpret_cast<const float4*>(hb + ((x0 + 128) ^ sw));
    float4 a3 = *reinterpret_cast<const float4*>(hb + ((x0 + 144) ^ sw));
    float4 b0 = *reinterpret_cast<const float4*>(wb + (x0 ^ swb));
    float4 b1 = *reinterpret_cast<const float4*>(wb + ((x0 + 16) ^ swb));
    float4 b2 = *reinterpret_cast<const float4*>(wb + ((x0 + 128) ^ swb));
    float4 b3 = *reinterpret_cast<const float4*>(wb + ((x0 + 144) ^ swb));
    short8 A0 = pack8(a0, a1), A1 = pack8(a2, a3);
    short8 B0 = pack8(b0, b1), B1 = pack8(b2, b3);
    WAIT_LGKM0;   // our ds_reads of chunk kc are in regs
    BARRIER();    // all waves done with buf[kc&1]
    if (kc < NCH - 2) STAGE(kc & 1, kc + 2);  // prefetch flies across barriers
    acc = __builtin_amdgcn_mfma_f32_16x16x32_bf16(A0, B0, acc, 0, 0, 0);
    acc = __builtin_amdgcn_mfma_f32_16x16x32_bf16(A1, B1, acc, 0, 0, 0);
  }
  {  // final chunk (NCH-1, odd -> buf1), full drain
    WAIT_VM(0);
    BARRIER();
    unsigned x0 = q * 32u;
    float4 a0 = *reinterpret_cast<const float4*>(hb1 + (x0 ^ sw));
    float4 a1 = *reinterpret_cast<const float4*>(hb1 + ((x0 + 16) ^ sw));
    float4 a2 = *reinterpret_cast<const float4*>(hb1 + ((x0 + 128) ^ sw));
    float4 a3 = *reinterpret_cast<const float4*>(hb1 + ((x0 + 144) ^ sw));
    float4 b0 = *reinterpret_cast<const float4*>(wb1 + (x0 ^ swb));
    float4 b1 = *reinterpret_cast<const float4*>(wb1 + ((x0 + 16) ^ swb));
    float4 b2 = *reinterpret_cast<const float4*>(wb1 + ((x0 + 128) ^ swb));
    float4 b3 = *reinterpret_cast<const float4*>(wb1 + ((x0 + 144) ^ swb));
    acc = __builtin_amdgcn_mfma_f32_16x16x32_bf16(pack8(a0, a1), pack8(b0, b1), acc, 0, 0, 0);
    acc = __builtin_amdgcn_mfma_f32_16x16x32_bf16(pack8(a2, a3), pack8(b2, b3), acc, 0, 0, 0);
  }

  // ---- 5) write gathered rows -> A_lds (bf16) ----
#pragma unroll
  for (int p = 0; p < 9; ++p) {
    int task = p * 256 + tid;
    int r = task >> 3, c4 = (task & 7) * 4;
    uint2v pk = {pk2(g[p].x, g[p].y), pk2(g[p].z, g[p].w)};
    *reinterpret_cast<uint2v*>(&A_lds[r >> 3][(r & 7) * 32 + c4]) = pk;
  }
  WAIT_LGKM0; BARRIER();

  // ---- 6) emb0 MFMA: 3 slot-tiles (bases 0,16,20) x 2 e-tiles = 6 jobs ----
  for (int job = wid; job < 6; job += 4) {
    int jt = job >> 1;
    int base = (jt == 0) ? 0 : (jt == 1) ? 16 : 20;
    int e0 = (job & 1) * 16;
    f32x4 ac = {0.f, 0.f, 0.f, 0.f};
#pragma unroll
    for (int ks = 0; ks < 8; ++ks) {
      short8 wf = load8_bf(Wh + (size_t)(e0 + l16) * 256 + ks * 32 + q * 8);
      short8 a = *reinterpret_cast<const short8*>(&A_lds[base + l16][ks * 32 + q * 8]);
      ac = __builtin_amdgcn_mfma_f32_16x16x32_bf16(wf, a, ac, 0, 0, 0);
    }
    // D: col=slot(l16), row=e(q*4+j); tile 2 overlaps tile 1 -> only write slots >=32
    if (jt != 2 || l16 >= 12)
      *reinterpret_cast<f32x4*>(&emb36[base + l16][e0 + q * 4]) = ac;
  }
  WAIT_LGKM0; BARRIER();

  // ---- 7) conv: out token t0+tl needs slots tl+1..tl+4 (batch zero-pad) ----
#pragma unroll
  for (int it = 0; it < 4; ++it) {
    int ii = it * 256 + tid;
    int tl = ii >> 5, e = ii & 31;
    int s = (t0 & 4095) + tl;
    float a = cb[e];
#pragma unroll
    for (int j = 0; j < 4; ++j)
      if (s - 3 + j >= 0) a += cw[e * 4 + j] * emb36[tl + 1 + j][e];
    emb_c[tl][e] = a;
  }
  WAIT_LGKM0; BARRIER();

  // ---- 8) sigmoid * conv-emb -> ge_lds (acc held from MLP; wave quadrant) ----
#pragma unroll
  for (int j = 0; j < 4; ++j) {
    int r = tt * 16 + q * 4 + j, c = ee * 16 + l16;
    float gt = 1.f / (1.f + __expf(-acc[j]));
    ge_lds[r][c] = f2bf(gt * emb_c[r][c]);
  }
  WAIT_LGKM0; BARRIER();

  // ---- 9) out[t,h] = ge @ Wo.T (swapped -> float4 stores); 512 h-cols/wave ----
  short8 Af0 = *reinterpret_cast<const short8*>(&ge_lds[l16][q * 8]);
  short8 Af1 = *reinterpret_cast<const short8*>(&ge_lds[16 + l16][q * 8]);
  float* orow0 = out + (size_t)(t0 + l16) * HSZ;
  float* orow1 = out + (size_t)(t0 + 16 + l16) * HSZ;
  int hbase = wid * 512;
  for (int ht = 0; ht < 32; ++ht) {
    int h0 = hbase + ht * 16;
    short8 aw = load8_bf(Wo + (size_t)(h0 + l16) * 32 + q * 8);
    f32x4 z = {0.f, 0.f, 0.f, 0.f};
    f32x4 o0 = __builtin_amdgcn_mfma_f32_16x16x32_bf16(aw, Af0, z, 0, 0, 0);
    f32x4 o1 = __builtin_amdgcn_mfma_f32_16x16x32_bf16(aw, Af1, z, 0, 0, 0);
    *reinterpret_cast<f32x4*>(orow0 + h0 + q * 4) = o0;
    *reinterpret_cast<f32x4*>(orow1 + h0 + q * 4) = o1;
  }
}

extern "C" void kernel_launch(void* const* d_in, const int* in_sizes, int n_in,
                              void* d_out, int out_size, void* d_ws, size_t ws_size,
                              hipStream_t stream) {
  const int* ids = (const int*)d_in[0];
  const float* hidden = (const float*)d_in[1];
  const int* mapping = (const int*)d_in[2];
  const unsigned* mult = (const unsigned*)d_in[3];  // delivered as int32; low bits exact
  const float* table = (const float*)d_in[4];
  const float* cw = (const float*)d_in[5];
  const float* cb = (const float*)d_in[6];
  const float* Wh = (const float*)d_in[7];
  const float* Wg = (const float*)d_in[8];
  const float* Wo = (const float*)d_in[9];
  float* out = (float*)d_out;

  engram_fused<<<512, 256, 0, stream>>>(ids, mapping, mult, table, Wh, hidden,
                                        cw, cb, Wg, Wo, out);
}